// Round 7
// baseline (247.010 us; speedup 1.0000x reference)
//
#include <hip/hip_runtime.h>

// Reference reduces to: out = box3x3_zeropad(x) + x + bias[c]
// (softmax over a size-1 axis == 1.0; the w1/w2 matmul branch is dead).
//
// x: (32, 256, 64, 64) fp32 -> 8192 planes of 64x64. Memory-bound stencil,
// traffic floor ~268 MB -> ~43 us at 6.3 TB/s.
//
// R3 postmortem: march kernel = 81 us == LDS kernel (82 us); VALUBusy 4.8%,
// occupancy 28%, HBM 2.5 TB/s -> latency-bound. Fix: 1 thread = 1 float4
// output, 3 independent row-loads issued up front, DPP horizontal halo,
// single store at end; full 32-wave/CU occupancy.
//
// R6 postmortem: FAILED correctness (absmax 18.6) -- grid was 2048 blocks
// but one-thread-per-float4 needs 8192*64*16 = 8,388,608 threads = 32768
// blocks (my "/256 = 2048" was off by 16x). Only planes 0..511 were
// written; the rest stayed memset-zero. Math per thread was already
// verified by R3 (passed, absmax 0.0625). This round: grid = 32768.

#define WW 64

__device__ __forceinline__ float dpp_shr1(float x) {
    // lane i <- lane i-1 within each 16-lane DPP row; first lane of row -> 0
    return __int_as_float(__builtin_amdgcn_update_dpp(
        0, __float_as_int(x), 0x111, 0xF, 0xF, true));
}
__device__ __forceinline__ float dpp_shl1(float x) {
    // lane i <- lane i+1 within each 16-lane DPP row; last lane of row -> 0
    return __int_as_float(__builtin_amdgcn_update_dpp(
        0, __float_as_int(x), 0x101, 0xF, 0xF, true));
}

// horizontal 3-tap box sum of a 64-col row distributed as 16 lanes x float4
__device__ __forceinline__ float4 hsum3(float4 v) {
    float lft = dpp_shr1(v.w);   // col-1 (left neighbor's .w; 0 at plane edge)
    float rgt = dpp_shl1(v.x);   // col+4 (right neighbor's .x; 0 at plane edge)
    float t1 = v.x + v.y;
    float t2 = v.y + v.z;
    float t3 = v.z + v.w;
    float4 h;
    h.x = lft + t1;
    h.y = t1 + v.z;
    h.z = t2 + v.w;
    h.w = t3 + rgt;
    return h;
}

__global__ __launch_bounds__(256) void dwconv_flat_kernel(
    const float* __restrict__ x,
    const float* __restrict__ bias,
    float* __restrict__ out)
{
    // gid -> (plane, row, seg): 8192 planes x 64 rows x 16 float4-segments.
    // 1024 gids per plane (64-divisible) -> a wave never straddles planes:
    // wave-uniform plane (scalar bias load), and each 16-lane DPP row holds
    // one full 64-col image row -> DPP halo semantics are exact.
    const int gid   = blockIdx.x * 256 + threadIdx.x;   // 0..8388607
    const int plane = gid >> 10;
    const int row   = (gid >> 4) & 63;
    const int seg   = gid & 15;

    const float* xp = x + ((size_t)plane << 12) + (row << 6) + (seg << 2);

    const float4 zero = make_float4(0.f, 0.f, 0.f, 0.f);
    // three independent loads, issued before any use
    float4 vm = (row > 0)  ? *reinterpret_cast<const float4*>(xp - WW) : zero;
    float4 vc =              *reinterpret_cast<const float4*>(xp);
    float4 vp = (row < 63) ? *reinterpret_cast<const float4*>(xp + WW) : zero;

    float4 hm = hsum3(vm);
    float4 hc = hsum3(vc);
    float4 hp = hsum3(vp);

    const float bv = bias[plane & 255];

    float4 o;
    o.x = hm.x + hc.x + hp.x + vc.x + bv;
    o.y = hm.y + hc.y + hp.y + vc.y + bv;
    o.z = hm.z + hc.z + hp.z + vc.z + bv;
    o.w = hm.w + hc.w + hp.w + vc.w + bv;

    *reinterpret_cast<float4*>(out + ((size_t)plane << 12) + (row << 6) + (seg << 2)) = o;
}

extern "C" void kernel_launch(void* const* d_in, const int* in_sizes, int n_in,
                              void* d_out, int out_size, void* d_ws, size_t ws_size,
                              hipStream_t stream)
{
    const float* x    = (const float*)d_in[0];
    // d_in[1..4] = w1, b1, w2, b2 : algebraically dead (softmax over size-1 axis == 1)
    const float* bias = (const float*)d_in[5];
    float* out        = (float*)d_out;

    // one thread per float4: 8192 planes * 64 rows * 16 segs = 8,388,608
    // threads = 32768 blocks of 256
    dwconv_flat_kernel<<<32768, 256, 0, stream>>>(x, bias, out);
}